// Round 4
// baseline (559.600 us; speedup 1.0000x reference)
//
#include <hip/hip_runtime.h>
#include <stdint.h>

// ---------------------------------------------------------------------------
// TransformerBlock for MI355X (gfx950)
// B=2, L=2048, E=1024, H=16, DH=64, FF=4096
// GEMMs: bf16 MFMA 16x16x32, 128-wide tiles, BK=64, XOR-swizzled
// global_load_lds staging. Flash attention: barrier-free, S^T formulation,
// K/V fragments direct global->VGPR (coalesced 16B), exp2-domain softmax.
// d_out is FP32.
// ---------------------------------------------------------------------------

typedef __attribute__((ext_vector_type(8))) short short8;
typedef __attribute__((ext_vector_type(4))) float floatx4;

extern "C" __device__ float __ocml_native_exp2_f32(float);
#define EXP2(x) __ocml_native_exp2_f32(x)

#define MFMA_BF16(a, b, c) __builtin_amdgcn_mfma_f32_16x16x32_bf16((a), (b), (c), 0, 0, 0)

__device__ __forceinline__ unsigned short f2bf(float f) {
  union { float f; unsigned int u; } v; v.f = f;
  unsigned int r = v.u + 0x7FFFu + ((v.u >> 16) & 1u);   // RNE
  return (unsigned short)(r >> 16);
}

__device__ __forceinline__ unsigned int f2u(float f) {
  union { float f; unsigned int u; } v; v.f = f; return v.u;
}

__device__ __forceinline__ void gl_lds16(const unsigned short* g, unsigned short* l) {
  __builtin_amdgcn_global_load_lds(
      (const __attribute__((address_space(1))) unsigned int*)g,
      (__attribute__((address_space(3))) unsigned int*)l, 16, 0, 0);
}

// ---------------------------------------------------------------------------
// GEMM: C[M x N] = A[M x K](bf16) * Bt[N x K]^T(bf16) + bias, M=4096, BK=64.
// BN=128: 4 waves in 2x2 (64x64 each). BN=64: 4 waves stacked in M (32x64).
// LDS rows (64 elem = 8 chunks of 8): chunk' = chunk ^ (row & 7).
// MODE 0: fused QKV (N=3072): q(bf16, x 8*log2e)/k/v head layout
// MODE 1: hidden(fp32) = res + c                  (out-proj + residual)
// MODE 2: bf16 gelu(c), stride 4096               (FFN up)
// MODE 3: fp32 res + c, stride 1024 -> d_out      (FFN down + residual)
// ---------------------------------------------------------------------------
template <int MODE, int BN>
__global__ __launch_bounds__(256)
void gemm_bt(const unsigned short* __restrict__ A,
             const unsigned short* __restrict__ Bt,
             const float* __restrict__ bias,
             void* __restrict__ outp,
             const float* __restrict__ res,
             int K,
             void* __restrict__ out2, void* __restrict__ out3,
             const float* __restrict__ bias2, const float* __restrict__ bias3) {
  constexpr int BM = 128, BK = 64;
  constexpr int MI = (BN == 128) ? 4 : 2;
  constexpr int NI = 4;
  __shared__ __align__(16) unsigned short As[BM * BK];
  __shared__ __align__(16) unsigned short Bs[BN * BK];
  const int tid = threadIdx.x;
  const int wave = tid >> 6, lane = tid & 63, l16 = lane & 15, quad = lane >> 4;
  const int m0 = blockIdx.y * BM, n0 = blockIdx.x * BN;
  const int wm = (BN == 128) ? (wave >> 1) * 64 : wave * 32;
  const int wn = (BN == 128) ? (wave & 1) * 64 : 0;
  const int sw = l16 & 7;                  // read-side swizzle (row&7 == l16&7)
  const int sl0 = (quad ^ sw) << 3;        // k-half 0 slot
  const int sl1 = sl0 ^ 32;                // k-half 1 slot ((quad^4)^sw)<<3

  floatx4 acc[MI][NI] = {};

  for (int k0 = 0; k0 < K; k0 += BK) {
    __syncthreads();
#pragma unroll
    for (int c = 0; c < (BM * BK) / 2048; ++c) {
      const int e = (c * 256 + tid) * 8;
      const int row = e >> 6, c8 = (e >> 3) & 7;
      gl_lds16(A + (size_t)(m0 + row) * K + k0 + ((c8 ^ (row & 7)) << 3), &As[e]);
    }
#pragma unroll
    for (int c = 0; c < (BN * BK) / 2048; ++c) {
      const int e = (c * 256 + tid) * 8;
      const int row = e >> 6, c8 = (e >> 3) & 7;
      gl_lds16(Bt + (size_t)(n0 + row) * K + k0 + ((c8 ^ (row & 7)) << 3), &Bs[e]);
    }
    __syncthreads();

    short8 af0[MI], af1[MI], bf0[NI], bf1[NI];
#pragma unroll
    for (int i = 0; i < MI; ++i) {
      af0[i] = *(const short8*)&As[(wm + i * 16 + l16) * BK + sl0];
      af1[i] = *(const short8*)&As[(wm + i * 16 + l16) * BK + sl1];
    }
#pragma unroll
    for (int i = 0; i < NI; ++i) {
      bf0[i] = *(const short8*)&Bs[(wn + i * 16 + l16) * BK + sl0];
      bf1[i] = *(const short8*)&Bs[(wn + i * 16 + l16) * BK + sl1];
    }
#pragma unroll
    for (int mi = 0; mi < MI; ++mi)
#pragma unroll
      for (int ni = 0; ni < NI; ++ni) {
        acc[mi][ni] = MFMA_BF16(af0[mi], bf0[ni], acc[mi][ni]);
        acc[mi][ni] = MFMA_BF16(af1[mi], bf1[ni], acc[mi][ni]);
      }
  }

  // epilogue
  const int seg = (MODE == 0) ? (n0 >> 10) : 0;   // block-uniform for BN=128
  const float* bptr = bias;
  if constexpr (MODE == 0) bptr = (seg == 0) ? bias : (seg == 1 ? bias2 : bias3);

  float bcol[NI];
#pragma unroll
  for (int ni = 0; ni < NI; ++ni) {
    const int n = n0 + wn + ni * 16 + l16;
    bcol[ni] = bptr[(MODE == 0) ? (n & 1023) : n];
  }

#pragma unroll
  for (int mi = 0; mi < MI; ++mi) {
#pragma unroll
    for (int r = 0; r < 4; ++r) {
      const int m = m0 + wm + mi * 16 + quad * 4 + r;
#pragma unroll
      for (int ni = 0; ni < NI; ++ni) {
        const int n = n0 + wn + ni * 16 + l16;
        const float c = acc[mi][ni][r] + bcol[ni];
        if constexpr (MODE == 0) {
          const int b_ = m >> 11, l = m & 2047, hd = n & 1023;
          const size_t idx =
              ((size_t)((b_ * 16 + (hd >> 6)) * 2048 + l)) * 64 + (hd & 63);
          if (seg == 0)       ((unsigned short*)outp)[idx] = f2bf(c * 11.5415603270f);
          else if (seg == 1)  ((unsigned short*)out2)[idx] = f2bf(c);
          else                ((unsigned short*)out3)[idx] = f2bf(c);
        } else if constexpr (MODE == 1) {
          ((float*)outp)[(size_t)m * 1024 + n] = res[(size_t)m * 1024 + n] + c;
        } else if constexpr (MODE == 2) {
          const float g = 0.5f * c * (1.0f + erff(c * 0.70710678118654752f));
          ((unsigned short*)outp)[(size_t)m * 4096 + n] = f2bf(g);
        } else {
          ((float*)outp)[(size_t)m * 1024 + n] = res[(size_t)m * 1024 + n] + c;
        }
      }
    }
  }
}

// ---------------------------------------------------------------------------
// LayerNorm: one block per row of 1024 fp32; bf16 output.
// ---------------------------------------------------------------------------
__global__ __launch_bounds__(256)
void layernorm_kernel(const float* __restrict__ x, const float* __restrict__ w,
                      const float* __restrict__ b, unsigned short* __restrict__ out) {
  const int row = blockIdx.x, tid = threadIdx.x;
  const int wave = tid >> 6, lane = tid & 63;
  const float4 v = ((const float4*)(x + (size_t)row * 1024))[tid];
  float s = v.x + v.y + v.z + v.w;
  float s2 = v.x * v.x + v.y * v.y + v.z * v.z + v.w * v.w;
#pragma unroll
  for (int off = 32; off > 0; off >>= 1) {
    s += __shfl_down(s, off);
    s2 += __shfl_down(s2, off);
  }
  __shared__ float red[8];
  if (lane == 0) { red[wave] = s; red[4 + wave] = s2; }
  __syncthreads();
  const float ts = red[0] + red[1] + red[2] + red[3];
  const float ts2 = red[4] + red[5] + red[6] + red[7];
  const float mu = ts * (1.0f / 1024.0f);
  const float var = ts2 * (1.0f / 1024.0f) - mu * mu;
  const float rs = rsqrtf(var + 1e-5f);
  const float4 wv = ((const float4*)w)[tid];
  const float4 bv = ((const float4*)b)[tid];
  ushort4 o;
  o.x = f2bf((v.x - mu) * rs * wv.x + bv.x);
  o.y = f2bf((v.y - mu) * rs * wv.y + bv.y);
  o.z = f2bf((v.z - mu) * rs * wv.z + bv.z);
  o.w = f2bf((v.w - mu) * rs * wv.w + bv.w);
  ((ushort4*)(out + (size_t)row * 1024))[tid] = o;
}

// ---------------------------------------------------------------------------
// Tiled transpose fp32[R][C] -> bf16[C][R]  (weight prep)
// ---------------------------------------------------------------------------
__global__ __launch_bounds__(256)
void transpose_cast(const float* __restrict__ in, unsigned short* __restrict__ out,
                    int R, int C) {
  __shared__ float tile[32][33];
  const int tx = threadIdx.x, ty = threadIdx.y;
  const int c0 = blockIdx.x * 32, r0 = blockIdx.y * 32;
#pragma unroll
  for (int i = 0; i < 4; ++i)
    tile[ty + 8 * i][tx] = in[(size_t)(r0 + ty + 8 * i) * C + c0 + tx];
  __syncthreads();
#pragma unroll
  for (int i = 0; i < 4; ++i)
    out[(size_t)(c0 + ty + 8 * i) * R + r0 + tx] = f2bf(tile[tx][ty + 8 * i]);
}

// Tiled transpose bf16[R][C] -> bf16[C][R] per head (z = head index)
__global__ __launch_bounds__(256)
void transpose_bf16(const unsigned short* __restrict__ in,
                    unsigned short* __restrict__ out, int R, int C) {
  __shared__ unsigned short tile[32][33];
  const size_t hoff = (size_t)blockIdx.z * R * C;
  in += hoff; out += hoff;
  const int tx = threadIdx.x, ty = threadIdx.y;
  const int c0 = blockIdx.x * 32, r0 = blockIdx.y * 32;
#pragma unroll
  for (int i = 0; i < 4; ++i)
    tile[ty + 8 * i][tx] = in[(size_t)(r0 + ty + 8 * i) * C + c0 + tx];
  __syncthreads();
#pragma unroll
  for (int i = 0; i < 4; ++i)
    out[(size_t)(c0 + ty + 8 * i) * R + r0 + tx] = tile[tx][ty + 8 * i];
}

// ---------------------------------------------------------------------------
// Flash attention v4: barrier-free, S^T formulation, exp2-domain softmax.
// q,k: [32][2048][64] bf16 (q pre-scaled by 8*log2e); v: [32][64][2048] bf16.
// Block = 64 q-rows x one bh; 4 independent waves, 16 q each.
// K/V fragments read DIRECTLY global->VGPR (coalesced 16B per lane);
// K double-buffered in registers across KV tiles; V loads issued at iter
// top, consumed after softmax. Only LDS use: wave-private P transform.
// ---------------------------------------------------------------------------
__global__ __launch_bounds__(256, 3)
void flash_attn(const unsigned short* __restrict__ q,
                const unsigned short* __restrict__ k,
                const unsigned short* __restrict__ v,
                unsigned short* __restrict__ ctx) {
  __shared__ __align__(16) unsigned short Ps[4][16 * 72];   // per-wave [q][kv]
  const int bh = blockIdx.y, qt = blockIdx.x;
  const int tid = threadIdx.x, wave = tid >> 6, lane = tid & 63;
  const int l16 = lane & 15, quad = lane >> 4;
  const int qrow = qt * 64 + wave * 16 + l16;
  const unsigned short* qp = q + (size_t)bh * 2048 * 64 + (size_t)qrow * 64;
  const short8 qf0 = *(const short8*)(qp + quad * 8);
  const short8 qf1 = *(const short8*)(qp + 32 + quad * 8);
  // per-lane fragment base pointers
  const unsigned short* kp = k + (size_t)bh * 2048 * 64 + (size_t)l16 * 64 + quad * 8;
  const unsigned short* vp = v + (size_t)bh * 64 * 2048 + (size_t)l16 * 2048 + quad * 8;

  floatx4 O[4] = {};
  float m_run = -1e30f, l_run = 0.f;

  short8 kc[8];
#pragma unroll
  for (int nt = 0; nt < 4; ++nt) {
    kc[2 * nt]     = *(const short8*)(kp + (size_t)(nt * 16) * 64);
    kc[2 * nt + 1] = *(const short8*)(kp + (size_t)(nt * 16) * 64 + 32);
  }

  for (int t = 0; t < 32; ++t) {
    const int kv0 = t * 64;
    const int kvn = (t < 31) ? kv0 + 64 : 0;   // clamp: last prefetch unused
    // prefetch K(t+1) into alternate registers (consumed at loop end)
    short8 kn[8];
#pragma unroll
    for (int nt = 0; nt < 4; ++nt) {
      kn[2 * nt]     = *(const short8*)(kp + (size_t)(kvn + nt * 16) * 64);
      kn[2 * nt + 1] = *(const short8*)(kp + (size_t)(kvn + nt * 16) * 64 + 32);
    }
    // V(t) loads — consumed only after softmax (latency hidden under it)
    short8 vf[8];
#pragma unroll
    for (int nt = 0; nt < 4; ++nt) {
      vf[2 * nt]     = *(const short8*)(vp + (size_t)(nt * 16) * 2048 + kv0);
      vf[2 * nt + 1] = *(const short8*)(vp + (size_t)(nt * 16) * 2048 + kv0 + 32);
    }

    // --- S^T = K . Q^T (log2 units: q pre-scaled by 8*log2e) ---
    floatx4 st[4];
#pragma unroll
    for (int nt = 0; nt < 4; ++nt) {
      floatx4 z = {};
      z = MFMA_BF16(kc[2 * nt], qf0, z);
      z = MFMA_BF16(kc[2 * nt + 1], qf1, z);
      st[nt] = z;
    }

    // --- online softmax, scalar state per lane (q = l16 column) ---
    float mx = st[0][0];
#pragma unroll
    for (int nt = 0; nt < 4; ++nt)
#pragma unroll
      for (int r = 0; r < 4; ++r) mx = fmaxf(mx, st[nt][r]);
    mx = fmaxf(mx, __shfl_xor(mx, 16));
    mx = fmaxf(mx, __shfl_xor(mx, 32));
    const float m_new = fmaxf(m_run, mx);
    const float alpha = EXP2(m_run - m_new);
    m_run = m_new;

    float rsum = 0.f;
#pragma unroll
    for (int nt = 0; nt < 4; ++nt) {
      const float p0 = EXP2(st[nt][0] - m_new);
      const float p1 = EXP2(st[nt][1] - m_new);
      const float p2 = EXP2(st[nt][2] - m_new);
      const float p3 = EXP2(st[nt][3] - m_new);
      rsum += (p0 + p1) + (p2 + p3);
      uint2 pk;
      pk.x = __builtin_amdgcn_perm(f2u(p1), f2u(p0), 0x07060302u);
      pk.y = __builtin_amdgcn_perm(f2u(p3), f2u(p2), 0x07060302u);
      *(uint2*)&Ps[wave][l16 * 72 + nt * 16 + quad * 4] = pk;
    }
    rsum += __shfl_xor(rsum, 16);
    rsum += __shfl_xor(rsum, 32);
    l_run = l_run * alpha + rsum;

#pragma unroll
    for (int nt = 0; nt < 4; ++nt) {
      O[nt][0] *= alpha; O[nt][1] *= alpha; O[nt][2] *= alpha; O[nt][3] *= alpha;
    }

    // --- O^T += V^T . P^T  (wave-private Ps round trip, no barrier) ---
    const short8 pf0 = *(const short8*)&Ps[wave][l16 * 72 + quad * 8];
    const short8 pf1 = *(const short8*)&Ps[wave][l16 * 72 + 32 + quad * 8];
#pragma unroll
    for (int nt = 0; nt < 4; ++nt) {
      O[nt] = MFMA_BF16(vf[2 * nt], pf0, O[nt]);
      O[nt] = MFMA_BF16(vf[2 * nt + 1], pf1, O[nt]);
    }
#pragma unroll
    for (int i = 0; i < 8; ++i) kc[i] = kn[i];
  }

  const float inv = 1.0f / l_run;
  const int b_ = bh >> 4, h = bh & 15;
  unsigned short* op = ctx + ((size_t)(b_ * 2048) + qrow) * 1024 + h * 64;
#pragma unroll
  for (int nt = 0; nt < 4; ++nt) {
    ushort4 o4;
    o4.x = f2bf(O[nt][0] * inv);
    o4.y = f2bf(O[nt][1] * inv);
    o4.z = f2bf(O[nt][2] * inv);
    o4.w = f2bf(O[nt][3] * inv);
    *(ushort4*)(op + nt * 16 + quad * 4) = o4;   // d = nt*16 + quad*4 + r
  }
}

// ---------------------------------------------------------------------------
// Launch
// ---------------------------------------------------------------------------
extern "C" void kernel_launch(void* const* d_in, const int* in_sizes, int n_in,
                              void* d_out, int out_size, void* d_ws, size_t ws_size,
                              hipStream_t stream) {
  const float* x     = (const float*)d_in[0];
  const float* ln1_w = (const float*)d_in[1];
  const float* ln1_b = (const float*)d_in[2];
  const float* wq    = (const float*)d_in[3];
  const float* bq    = (const float*)d_in[4];
  const float* wk    = (const float*)d_in[5];
  const float* bk    = (const float*)d_in[6];
  const float* wv    = (const float*)d_in[7];
  const float* bv    = (const float*)d_in[8];
  const float* wo    = (const float*)d_in[9];
  const float* bo    = (const float*)d_in[10];
  const float* ln2_w = (const float*)d_in[11];
  const float* ln2_b = (const float*)d_in[12];
  const float* wu    = (const float*)d_in[13];
  const float* bu    = (const float*)d_in[14];
  const float* wd    = (const float*)d_in[15];
  const float* bd    = (const float*)d_in[16];

  char* W = (char*)d_ws;
  const size_t MB = 1ull << 20;
  unsigned short* wqkvT = (unsigned short*)(W + 0 * MB);  // [3072][1024]
  unsigned short* woT   = (unsigned short*)(W + 6 * MB);  // [1024][1024]
  unsigned short* wuT   = (unsigned short*)(W + 8 * MB);  // [4096][1024]
  unsigned short* wdT   = (unsigned short*)(W + 16 * MB); // [1024][4096]
  unsigned short* xn    = (unsigned short*)(W + 24 * MB); // [4096][1024]
  unsigned short* qb    = (unsigned short*)(W + 32 * MB); // [32][2048][64]
  unsigned short* kb    = (unsigned short*)(W + 40 * MB);
  unsigned short* vb    = (unsigned short*)(W + 48 * MB); // [32][64][2048]
  unsigned short* cx    = (unsigned short*)(W + 56 * MB); // vnat -> ctx -> hn
  float*          hid   = (float*)(W + 64 * MB);          // [4096][1024] fp32
  unsigned short* up    = (unsigned short*)(W + 24 * MB); // [4096][4096] (reuse)

  const dim3 tb(32, 8);
  // --- weight prep (bf16, transposed) ---
  transpose_cast<<<dim3(32, 32), tb, 0, stream>>>(wq, wqkvT, 1024, 1024);
  transpose_cast<<<dim3(32, 32), tb, 0, stream>>>(wk, wqkvT + 1024 * 1024, 1024, 1024);
  transpose_cast<<<dim3(32, 32), tb, 0, stream>>>(wv, wqkvT + 2048 * 1024, 1024, 1024);
  transpose_cast<<<dim3(32, 32), tb, 0, stream>>>(wo, woT, 1024, 1024);
  transpose_cast<<<dim3(128, 32), tb, 0, stream>>>(wu, wuT, 1024, 4096);
  transpose_cast<<<dim3(32, 128), tb, 0, stream>>>(wd, wdT, 4096, 1024);

  // --- attention block ---
  layernorm_kernel<<<4096, 256, 0, stream>>>(x, ln1_w, ln1_b, xn);
  gemm_bt<0, 128><<<dim3(24, 32), 256, 0, stream>>>(
      xn, wqkvT, bq, qb, nullptr, 1024, kb, cx, bk, bv);
  transpose_bf16<<<dim3(2, 64, 32), tb, 0, stream>>>(cx, vb, 2048, 64);
  flash_attn<<<dim3(32, 32), 256, 0, stream>>>(qb, kb, vb, cx);
  gemm_bt<1, 64><<<dim3(16, 32), 256, 0, stream>>>(
      cx, woT, bo, hid, x, 1024, nullptr, nullptr, nullptr, nullptr);

  // --- FFN block ---
  layernorm_kernel<<<4096, 256, 0, stream>>>(hid, ln2_w, ln2_b, cx);
  gemm_bt<2, 128><<<dim3(32, 32), 256, 0, stream>>>(
      cx, wuT, bu, up, nullptr, 1024, nullptr, nullptr, nullptr, nullptr);
  gemm_bt<3, 64><<<dim3(16, 32), 256, 0, stream>>>(
      up, wdT, bd, d_out, hid, 4096, nullptr, nullptr, nullptr, nullptr);
}

// Round 5
// 380.649 us; speedup vs baseline: 1.4701x; 1.4701x over previous
//
#include <hip/hip_runtime.h>
#include <stdint.h>

// ---------------------------------------------------------------------------
// TransformerBlock for MI355X (gfx950)
// B=2, L=2048, E=1024, H=16, DH=64, FF=4096
// GEMMs: bf16 MFMA 16x16x32, 128-wide tiles, BK=64, XOR-swizzled
// global_load_lds staging. Flash attention: LDS-staged double-buffered K/V
// (r3 structure — direct-to-VGPR fragments regressed 2.3x in r4), S^T
// formulation, exp2-domain softmax, Q-tile 128 (2 q-groups share K/V frags).
// d_out is FP32.
// ---------------------------------------------------------------------------

typedef __attribute__((ext_vector_type(8))) short short8;
typedef __attribute__((ext_vector_type(4))) float floatx4;

extern "C" __device__ float __ocml_native_exp2_f32(float);
#define EXP2(x) __ocml_native_exp2_f32(x)

#define MFMA_BF16(a, b, c) __builtin_amdgcn_mfma_f32_16x16x32_bf16((a), (b), (c), 0, 0, 0)

__device__ __forceinline__ unsigned short f2bf(float f) {
  union { float f; unsigned int u; } v; v.f = f;
  unsigned int r = v.u + 0x7FFFu + ((v.u >> 16) & 1u);   // RNE
  return (unsigned short)(r >> 16);
}

__device__ __forceinline__ unsigned int f2u(float f) {
  union { float f; unsigned int u; } v; v.f = f; return v.u;
}

__device__ __forceinline__ void gl_lds16(const unsigned short* g, unsigned short* l) {
  __builtin_amdgcn_global_load_lds(
      (const __attribute__((address_space(1))) unsigned int*)g,
      (__attribute__((address_space(3))) unsigned int*)l, 16, 0, 0);
}

// ---------------------------------------------------------------------------
// GEMM: C[M x N] = A[M x K](bf16) * Bt[N x K]^T(bf16) + bias, M=4096, BK=64.
// BN=128: 4 waves in 2x2 (64x64 each). BN=64: 4 waves stacked in M (32x64).
// LDS rows (64 elem = 8 chunks of 8): chunk' = chunk ^ (row & 7).
// MODE 0: fused QKV (N=3072): q(bf16, x 8*log2e)/k/v head layout
// MODE 1: hidden(fp32) = res + c                  (out-proj + residual)
// MODE 2: bf16 gelu(c), stride 4096               (FFN up)
// MODE 3: fp32 res + c, stride 1024 -> d_out      (FFN down + residual)
// ---------------------------------------------------------------------------
template <int MODE, int BN>
__global__ __launch_bounds__(256)
void gemm_bt(const unsigned short* __restrict__ A,
             const unsigned short* __restrict__ Bt,
             const float* __restrict__ bias,
             void* __restrict__ outp,
             const float* __restrict__ res,
             int K,
             void* __restrict__ out2, void* __restrict__ out3,
             const float* __restrict__ bias2, const float* __restrict__ bias3) {
  constexpr int BM = 128, BK = 64;
  constexpr int MI = (BN == 128) ? 4 : 2;
  constexpr int NI = 4;
  __shared__ __align__(16) unsigned short As[BM * BK];
  __shared__ __align__(16) unsigned short Bs[BN * BK];
  const int tid = threadIdx.x;
  const int wave = tid >> 6, lane = tid & 63, l16 = lane & 15, quad = lane >> 4;
  const int m0 = blockIdx.y * BM, n0 = blockIdx.x * BN;
  const int wm = (BN == 128) ? (wave >> 1) * 64 : wave * 32;
  const int wn = (BN == 128) ? (wave & 1) * 64 : 0;
  const int sw = l16 & 7;                  // read-side swizzle (row&7 == l16&7)
  const int sl0 = (quad ^ sw) << 3;        // k-half 0 slot
  const int sl1 = sl0 ^ 32;                // k-half 1 slot

  floatx4 acc[MI][NI] = {};

  for (int k0 = 0; k0 < K; k0 += BK) {
    __syncthreads();
#pragma unroll
    for (int c = 0; c < (BM * BK) / 2048; ++c) {
      const int e = (c * 256 + tid) * 8;
      const int row = e >> 6, c8 = (e >> 3) & 7;
      gl_lds16(A + (size_t)(m0 + row) * K + k0 + ((c8 ^ (row & 7)) << 3), &As[e]);
    }
#pragma unroll
    for (int c = 0; c < (BN * BK) / 2048; ++c) {
      const int e = (c * 256 + tid) * 8;
      const int row = e >> 6, c8 = (e >> 3) & 7;
      gl_lds16(Bt + (size_t)(n0 + row) * K + k0 + ((c8 ^ (row & 7)) << 3), &Bs[e]);
    }
    __syncthreads();

    short8 af0[MI], af1[MI], bf0[NI], bf1[NI];
#pragma unroll
    for (int i = 0; i < MI; ++i) {
      af0[i] = *(const short8*)&As[(wm + i * 16 + l16) * BK + sl0];
      af1[i] = *(const short8*)&As[(wm + i * 16 + l16) * BK + sl1];
    }
#pragma unroll
    for (int i = 0; i < NI; ++i) {
      bf0[i] = *(const short8*)&Bs[(wn + i * 16 + l16) * BK + sl0];
      bf1[i] = *(const short8*)&Bs[(wn + i * 16 + l16) * BK + sl1];
    }
#pragma unroll
    for (int mi = 0; mi < MI; ++mi)
#pragma unroll
      for (int ni = 0; ni < NI; ++ni) {
        acc[mi][ni] = MFMA_BF16(af0[mi], bf0[ni], acc[mi][ni]);
        acc[mi][ni] = MFMA_BF16(af1[mi], bf1[ni], acc[mi][ni]);
      }
  }

  // epilogue
  const int seg = (MODE == 0) ? (n0 >> 10) : 0;   // block-uniform for BN=128
  const float* bptr = bias;
  if constexpr (MODE == 0) bptr = (seg == 0) ? bias : (seg == 1 ? bias2 : bias3);

  float bcol[NI];
#pragma unroll
  for (int ni = 0; ni < NI; ++ni) {
    const int n = n0 + wn + ni * 16 + l16;
    bcol[ni] = bptr[(MODE == 0) ? (n & 1023) : n];
  }

#pragma unroll
  for (int mi = 0; mi < MI; ++mi) {
#pragma unroll
    for (int r = 0; r < 4; ++r) {
      const int m = m0 + wm + mi * 16 + quad * 4 + r;
#pragma unroll
      for (int ni = 0; ni < NI; ++ni) {
        const int n = n0 + wn + ni * 16 + l16;
        const float c = acc[mi][ni][r] + bcol[ni];
        if constexpr (MODE == 0) {
          const int b_ = m >> 11, l = m & 2047, hd = n & 1023;
          const size_t idx =
              ((size_t)((b_ * 16 + (hd >> 6)) * 2048 + l)) * 64 + (hd & 63);
          if (seg == 0)       ((unsigned short*)outp)[idx] = f2bf(c * 11.5415603270f);
          else if (seg == 1)  ((unsigned short*)out2)[idx] = f2bf(c);
          else                ((unsigned short*)out3)[idx] = f2bf(c);
        } else if constexpr (MODE == 1) {
          ((float*)outp)[(size_t)m * 1024 + n] = res[(size_t)m * 1024 + n] + c;
        } else if constexpr (MODE == 2) {
          const float g = 0.5f * c * (1.0f + erff(c * 0.70710678118654752f));
          ((unsigned short*)outp)[(size_t)m * 4096 + n] = f2bf(g);
        } else {
          ((float*)outp)[(size_t)m * 1024 + n] = res[(size_t)m * 1024 + n] + c;
        }
      }
    }
  }
}

// ---------------------------------------------------------------------------
// LayerNorm: one block per row of 1024 fp32; bf16 output.
// ---------------------------------------------------------------------------
__global__ __launch_bounds__(256)
void layernorm_kernel(const float* __restrict__ x, const float* __restrict__ w,
                      const float* __restrict__ b, unsigned short* __restrict__ out) {
  const int row = blockIdx.x, tid = threadIdx.x;
  const int wave = tid >> 6, lane = tid & 63;
  const float4 v = ((const float4*)(x + (size_t)row * 1024))[tid];
  float s = v.x + v.y + v.z + v.w;
  float s2 = v.x * v.x + v.y * v.y + v.z * v.z + v.w * v.w;
#pragma unroll
  for (int off = 32; off > 0; off >>= 1) {
    s += __shfl_down(s, off);
    s2 += __shfl_down(s2, off);
  }
  __shared__ float red[8];
  if (lane == 0) { red[wave] = s; red[4 + wave] = s2; }
  __syncthreads();
  const float ts = red[0] + red[1] + red[2] + red[3];
  const float ts2 = red[4] + red[5] + red[6] + red[7];
  const float mu = ts * (1.0f / 1024.0f);
  const float var = ts2 * (1.0f / 1024.0f) - mu * mu;
  const float rs = rsqrtf(var + 1e-5f);
  const float4 wv = ((const float4*)w)[tid];
  const float4 bv = ((const float4*)b)[tid];
  ushort4 o;
  o.x = f2bf((v.x - mu) * rs * wv.x + bv.x);
  o.y = f2bf((v.y - mu) * rs * wv.y + bv.y);
  o.z = f2bf((v.z - mu) * rs * wv.z + bv.z);
  o.w = f2bf((v.w - mu) * rs * wv.w + bv.w);
  ((ushort4*)(out + (size_t)row * 1024))[tid] = o;
}

// ---------------------------------------------------------------------------
// Fused 4-way tiled transpose fp32[1024][1024] -> bf16[1024][1024]^T
// z selects {wq,wk,wv,wo}; dst segments contiguous (wqkvT then woT).
// ---------------------------------------------------------------------------
__global__ __launch_bounds__(256)
void transpose_cast4(const float* __restrict__ s0, const float* __restrict__ s1,
                     const float* __restrict__ s2, const float* __restrict__ s3,
                     unsigned short* __restrict__ dst) {
  __shared__ float tile[32][33];
  const int z = blockIdx.z;
  const float* in = (z == 0) ? s0 : (z == 1) ? s1 : (z == 2) ? s2 : s3;
  unsigned short* out = dst + (size_t)z * 1024 * 1024;
  const int tx = threadIdx.x, ty = threadIdx.y;
  const int c0 = blockIdx.x * 32, r0 = blockIdx.y * 32;
#pragma unroll
  for (int i = 0; i < 4; ++i)
    tile[ty + 8 * i][tx] = in[(size_t)(r0 + ty + 8 * i) * 1024 + c0 + tx];
  __syncthreads();
#pragma unroll
  for (int i = 0; i < 4; ++i)
    out[(size_t)(c0 + ty + 8 * i) * 1024 + r0 + tx] = f2bf(tile[tx][ty + 8 * i]);
}

// Tiled transpose fp32[R][C] -> bf16[C][R]  (wu/wd prep)
__global__ __launch_bounds__(256)
void transpose_cast(const float* __restrict__ in, unsigned short* __restrict__ out,
                    int R, int C) {
  __shared__ float tile[32][33];
  const int tx = threadIdx.x, ty = threadIdx.y;
  const int c0 = blockIdx.x * 32, r0 = blockIdx.y * 32;
#pragma unroll
  for (int i = 0; i < 4; ++i)
    tile[ty + 8 * i][tx] = in[(size_t)(r0 + ty + 8 * i) * C + c0 + tx];
  __syncthreads();
#pragma unroll
  for (int i = 0; i < 4; ++i)
    out[(size_t)(c0 + ty + 8 * i) * R + r0 + tx] = f2bf(tile[tx][ty + 8 * i]);
}

// Tiled transpose bf16[R][C] -> bf16[C][R] per head (z = head index)
__global__ __launch_bounds__(256)
void transpose_bf16(const unsigned short* __restrict__ in,
                    unsigned short* __restrict__ out, int R, int C) {
  __shared__ unsigned short tile[32][33];
  const size_t hoff = (size_t)blockIdx.z * R * C;
  in += hoff; out += hoff;
  const int tx = threadIdx.x, ty = threadIdx.y;
  const int c0 = blockIdx.x * 32, r0 = blockIdx.y * 32;
#pragma unroll
  for (int i = 0; i < 4; ++i)
    tile[ty + 8 * i][tx] = in[(size_t)(r0 + ty + 8 * i) * C + c0 + tx];
  __syncthreads();
#pragma unroll
  for (int i = 0; i < 4; ++i)
    out[(size_t)(c0 + ty + 8 * i) * R + r0 + tx] = tile[tx][ty + 8 * i];
}

// ---------------------------------------------------------------------------
// Flash attention v5: LDS-staged double-buffered K/V (swizzled), S^T form,
// exp2-domain softmax, Q-tile 128 = 2 q-groups per wave sharing K/V frags.
// q,k: [32][2048][64] bf16 (q pre-scaled by 8*log2e); v: [32][64][2048] bf16.
// Block = 128 q-rows x one bh; 4 waves; wave handles q groups
// {qt*128 + g*64 + wave*16 + l16 : g=0,1}. KV tiles of 64.
// ---------------------------------------------------------------------------
__global__ __launch_bounds__(256)
void flash_attn(const unsigned short* __restrict__ q,
                const unsigned short* __restrict__ k,
                const unsigned short* __restrict__ v,
                unsigned short* __restrict__ ctx) {
  __shared__ __align__(16) unsigned short Ks[2][64 * 64];   // [kv][dh], swizzled
  __shared__ __align__(16) unsigned short Vs[2][64 * 64];   // [dh][kv], swizzled
  __shared__ __align__(16) unsigned short Ps[4][2][16 * 72];// [wave][g][q][kv]
  const int bh = blockIdx.y, qt = blockIdx.x;
  const int tid = threadIdx.x, wave = tid >> 6, lane = tid & 63;
  const int l16 = lane & 15, quad = lane >> 4;
  const unsigned short* kb = k + (size_t)bh * 2048 * 64;
  const unsigned short* vb = v + (size_t)bh * 64 * 2048;

  int qrow[2];
  short8 qf0[2], qf1[2];
#pragma unroll
  for (int g = 0; g < 2; ++g) {
    qrow[g] = qt * 128 + g * 64 + wave * 16 + l16;
    const unsigned short* qp = q + (size_t)bh * 2048 * 64 + (size_t)qrow[g] * 64;
    qf0[g] = *(const short8*)(qp + quad * 8);
    qf1[g] = *(const short8*)(qp + 32 + quad * 8);
  }

  floatx4 O[2][4] = {};
  float m_run[2] = {-1e30f, -1e30f}, l_run[2] = {0.f, 0.f};

  auto stage = [&](int t, int bufi) {
    const int kv0 = t * 64;
#pragma unroll
    for (int c = 0; c < 2; ++c) {
      const int e = (c * 256 + tid) * 8;
      const int r = e >> 6, ch = (e >> 3) & 7;
      const int sc = ((ch ^ (r & 7)) << 3);
      gl_lds16(kb + (size_t)(kv0 + r) * 64 + sc, &Ks[bufi][e]);
      gl_lds16(vb + (size_t)r * 2048 + kv0 + sc, &Vs[bufi][e]);
    }
  };
  stage(0, 0);

  const int sw = l16 & 7;
  const int sl0 = (quad ^ sw) << 3, sl1 = sl0 ^ 32;

  for (int t = 0; t < 32; ++t) {
    __syncthreads();                 // stage(t) complete; prev-buf reads done
    const int bufi = t & 1;
    if (t + 1 < 32) stage(t + 1, bufi ^ 1);

    // --- S^T = K . Q^T for both groups (K frags read once) ---
    floatx4 st[2][4];
#pragma unroll
    for (int nt = 0; nt < 4; ++nt) {
      const int r0 = (nt * 16 + l16) * 64;
      const short8 kf0 = *(const short8*)&Ks[bufi][r0 + sl0];
      const short8 kf1 = *(const short8*)&Ks[bufi][r0 + sl1];
#pragma unroll
      for (int g = 0; g < 2; ++g) {
        floatx4 z = {};
        z = MFMA_BF16(kf0, qf0[g], z);
        z = MFMA_BF16(kf1, qf1[g], z);
        st[g][nt] = z;
      }
    }

    // --- online softmax per group (scalar state per lane; q = l16 col) ---
    short8 pf0[2], pf1[2];
#pragma unroll
    for (int g = 0; g < 2; ++g) {
      float mx = st[g][0][0];
#pragma unroll
      for (int nt = 0; nt < 4; ++nt)
#pragma unroll
        for (int r = 0; r < 4; ++r) mx = fmaxf(mx, st[g][nt][r]);
      mx = fmaxf(mx, __shfl_xor(mx, 16));
      mx = fmaxf(mx, __shfl_xor(mx, 32));
      const float m_new = fmaxf(m_run[g], mx);
      const float alpha = EXP2(m_run[g] - m_new);
      m_run[g] = m_new;

      float rsum = 0.f;
#pragma unroll
      for (int nt = 0; nt < 4; ++nt) {
        const float p0 = EXP2(st[g][nt][0] - m_new);
        const float p1 = EXP2(st[g][nt][1] - m_new);
        const float p2 = EXP2(st[g][nt][2] - m_new);
        const float p3 = EXP2(st[g][nt][3] - m_new);
        rsum += (p0 + p1) + (p2 + p3);
        uint2 pk;
        pk.x = __builtin_amdgcn_perm(f2u(p1), f2u(p0), 0x07060302u);
        pk.y = __builtin_amdgcn_perm(f2u(p3), f2u(p2), 0x07060302u);
        *(uint2*)&Ps[wave][g][l16 * 72 + nt * 16 + quad * 4] = pk;
      }
      rsum += __shfl_xor(rsum, 16);
      rsum += __shfl_xor(rsum, 32);
      l_run[g] = l_run[g] * alpha + rsum;

#pragma unroll
      for (int nt = 0; nt < 4; ++nt) {
        O[g][nt][0] *= alpha; O[g][nt][1] *= alpha;
        O[g][nt][2] *= alpha; O[g][nt][3] *= alpha;
      }
      pf0[g] = *(const short8*)&Ps[wave][g][l16 * 72 + quad * 8];
      pf1[g] = *(const short8*)&Ps[wave][g][l16 * 72 + 32 + quad * 8];
    }

    // --- O^T += V^T . P^T (V frags read once, shared by both groups) ---
#pragma unroll
    for (int nt = 0; nt < 4; ++nt) {
      const int r0 = (nt * 16 + l16) * 64;
      const short8 vf0 = *(const short8*)&Vs[bufi][r0 + sl0];
      const short8 vf1 = *(const short8*)&Vs[bufi][r0 + sl1];
#pragma unroll
      for (int g = 0; g < 2; ++g) {
        O[g][nt] = MFMA_BF16(vf0, pf0[g], O[g][nt]);
        O[g][nt] = MFMA_BF16(vf1, pf1[g], O[g][nt]);
      }
    }
  }

  const int b_ = bh >> 4, h = bh & 15;
#pragma unroll
  for (int g = 0; g < 2; ++g) {
    const float inv = 1.0f / l_run[g];
    unsigned short* op = ctx + ((size_t)(b_ * 2048) + qrow[g]) * 1024 + h * 64;
#pragma unroll
    for (int nt = 0; nt < 4; ++nt) {
      ushort4 o4;
      o4.x = f2bf(O[g][nt][0] * inv);
      o4.y = f2bf(O[g][nt][1] * inv);
      o4.z = f2bf(O[g][nt][2] * inv);
      o4.w = f2bf(O[g][nt][3] * inv);
      *(ushort4*)(op + nt * 16 + quad * 4) = o4;   // d = nt*16 + quad*4 + r
    }
  }
}

// ---------------------------------------------------------------------------
// Launch
// ---------------------------------------------------------------------------
extern "C" void kernel_launch(void* const* d_in, const int* in_sizes, int n_in,
                              void* d_out, int out_size, void* d_ws, size_t ws_size,
                              hipStream_t stream) {
  const float* x     = (const float*)d_in[0];
  const float* ln1_w = (const float*)d_in[1];
  const float* ln1_b = (const float*)d_in[2];
  const float* wq    = (const float*)d_in[3];
  const float* bq    = (const float*)d_in[4];
  const float* wk    = (const float*)d_in[5];
  const float* bk    = (const float*)d_in[6];
  const float* wv    = (const float*)d_in[7];
  const float* bv    = (const float*)d_in[8];
  const float* wo    = (const float*)d_in[9];
  const float* bo    = (const float*)d_in[10];
  const float* ln2_w = (const float*)d_in[11];
  const float* ln2_b = (const float*)d_in[12];
  const float* wu    = (const float*)d_in[13];
  const float* bu    = (const float*)d_in[14];
  const float* wd    = (const float*)d_in[15];
  const float* bd    = (const float*)d_in[16];

  char* W = (char*)d_ws;
  const size_t MB = 1ull << 20;
  unsigned short* wqkvT = (unsigned short*)(W + 0 * MB);  // [3072][1024]
  unsigned short* woT   = (unsigned short*)(W + 6 * MB);  // [1024][1024] (contiguous after wqkvT)
  unsigned short* wuT   = (unsigned short*)(W + 8 * MB);  // [4096][1024]
  unsigned short* wdT   = (unsigned short*)(W + 16 * MB); // [1024][4096]
  unsigned short* xn    = (unsigned short*)(W + 24 * MB); // [4096][1024]
  unsigned short* qb    = (unsigned short*)(W + 32 * MB); // [32][2048][64]
  unsigned short* kb    = (unsigned short*)(W + 40 * MB);
  unsigned short* vb    = (unsigned short*)(W + 48 * MB); // [32][64][2048]
  unsigned short* cx    = (unsigned short*)(W + 56 * MB); // vnat -> ctx -> hn
  float*          hid   = (float*)(W + 64 * MB);          // [4096][1024] fp32
  unsigned short* up    = (unsigned short*)(W + 24 * MB); // [4096][4096] (reuse)

  const dim3 tb(32, 8);
  // --- weight prep (bf16, transposed) ---
  transpose_cast4<<<dim3(32, 32, 4), tb, 0, stream>>>(wq, wk, wv, wo, wqkvT);
  transpose_cast<<<dim3(128, 32), tb, 0, stream>>>(wu, wuT, 1024, 4096);
  transpose_cast<<<dim3(32, 128), tb, 0, stream>>>(wd, wdT, 4096, 1024);

  // --- attention block ---
  layernorm_kernel<<<4096, 256, 0, stream>>>(x, ln1_w, ln1_b, xn);
  gemm_bt<0, 128><<<dim3(24, 32), 256, 0, stream>>>(
      xn, wqkvT, bq, qb, nullptr, 1024, kb, cx, bk, bv);
  transpose_bf16<<<dim3(2, 64, 32), tb, 0, stream>>>(cx, vb, 2048, 64);
  flash_attn<<<dim3(16, 32), 256, 0, stream>>>(qb, kb, vb, cx);
  gemm_bt<1, 64><<<dim3(16, 32), 256, 0, stream>>>(
      cx, woT, bo, hid, x, 1024, nullptr, nullptr, nullptr, nullptr);

  // --- FFN block ---
  layernorm_kernel<<<4096, 256, 0, stream>>>(hid, ln2_w, ln2_b, cx);
  gemm_bt<2, 128><<<dim3(32, 32), 256, 0, stream>>>(
      cx, wuT, bu, up, nullptr, 1024, nullptr, nullptr, nullptr, nullptr);
  gemm_bt<3, 64><<<dim3(16, 32), 256, 0, stream>>>(
      up, wdT, bd, d_out, hid, 4096, nullptr, nullptr, nullptr, nullptr);
}